// Round 8
// baseline (176.745 us; speedup 1.0000x reference)
//
#include <hip/hip_runtime.h>

// WeightedDiceLoss on MI355X -- round 15: XCD producer/consumer alignment.
// R14 analysis: fixed harness overhead = 100+-2 us (268 MB ws poison fill at
// 6.6 TB/s + memsets); k1+k2 sum ~73 us, both < 40.4 us (absent from top-5),
// both ~2x their traffic floors. Suspect #1: k2's XCD swizzle SCATTERS blocks
// away from the XCD whose L2 holds the hrow rows k1 just wrote -> all 184 MB
// of hrow reads (127 MB of it the 31-row inits) pay cross-XCD L3 latency.
// Fix: both kernels use 1024 blocks in NATURAL order; k1 block g writes hrow
// rows [32g, 32g+32), k2 block g reads rows [32g-16, 32g+47] -> ~70% from the
// SAME XCD's L2 (round-robin block->XCD is stable across dispatches).
// Suspect #2: k1 computed row-by-row (load -> 17-shuffle chain -> store
// serially); now 8 rows/wave with ALL 16 loads issued before any compute.
//
// input, target: (64,1,512,512) fp32. Output: scalar fp32.
// weight = 1 + 5*|box31(target) - target|; loss = 1 - (2*I+1)/(A+B+1).

#define BATCH 64
#define H     512
#define W     512
#define PADT  16                       // top zero rows (image rows -16..-1)
#define PADB  15                       // bottom zero rows (rows 512..526)
#define HP    (H + PADT + PADB)        // 543 padded hrow rows per image
#define K1_BLOCKS 1024                 // 4096 waves x 8 rows = 32768 rows
#define RB    8                        // rows per k2 wave-task
#define K2_BLOCKS 1024                 // 4096 wave-tasks: 64 img x 64 bands

typedef _Float16 half8  __attribute__((ext_vector_type(8)));
typedef float    floatx4 __attribute__((ext_vector_type(4)));

// ---------------------------------------------------------------------------
// k1: hrow[r][x] = sum_{dx=-15..15} tgt[r][x+dx] (zero col padding), fp16,
// stored at padded row (r&511)+PADT of image r>>9. Also zeroes the pad rows.
// Block g covers global rows [32g, 32g+32) -- aligned with k2 block g.
// ---------------------------------------------------------------------------
__global__ __launch_bounds__(256) void hrow_kernel(const float* __restrict__ tgt,
                                                   _Float16* __restrict__ hbuf) {
    const int tid  = threadIdx.x;
    const int lane = tid & 63;
    const int wid  = blockIdx.x * 4 + (tid >> 6);   // 0..4095
    const int col0 = lane * 8;
    const int r0   = wid * 8;                       // first of 8 rows

    const float mL1 = (lane >= 1) ? 1.f : 0.f;
    const float mR1 = (lane <= 62) ? 1.f : 0.f;
    const float mL2 = (lane >= 2) ? 1.f : 0.f;
    const float mR2 = (lane <= 61) ? 1.f : 0.f;

    // ---- zero the pad rows (16 top + 15 bottom per image) -----------------
    if (wid < BATCH * 32) {
        const int img = wid >> 5, p = wid & 31;     // p = 0..31
        if (p < 31) {
            const int row = (p < PADT) ? p : p + H; // [0,16) u [528,543)
            half8 z = {};
            *(half8*)(hbuf + ((size_t)img * HP + row) * W + col0) = z;
        }
    }

    // ---- issue ALL 16 row loads up front (max loads in flight) ------------
    floatx4 va[8][2];
    #pragma unroll
    for (int k = 0; k < 8; ++k) {
        const float* trow = tgt + (size_t)(r0 + k) * W + col0;
        va[k][0] = *(const floatx4*)(trow);
        va[k][1] = *(const floatx4*)(trow + 4);
    }

    // ---- 8 horizontal 31-windows (verified segment-sum) -------------------
    #pragma unroll
    for (int k = 0; k < 8; ++k) {
        const float p1 = va[k][0][0];
        const float p2 = p1 + va[k][0][1];
        const float p3 = p2 + va[k][0][2];
        const float p4 = p3 + va[k][0][3];
        const float p5 = p4 + va[k][1][0];
        const float p6 = p5 + va[k][1][1];
        const float p7 = p6 + va[k][1][2];
        const float s  = p7 + va[k][1][3];
        const float f1 = s - p1, f2 = s - p2, f3 = s - p3, f4 = s - p4;
        const float f5 = s - p5, f6 = s - p6, f7 = s - p7;

        const float sL1 = __shfl_up(s, 1, 64);
        const float sR1 = __shfl_down(s, 1, 64);
        const float g1 = __shfl_up(f1, 2, 64);
        const float g2 = __shfl_up(f2, 2, 64);
        const float g3 = __shfl_up(f3, 2, 64);
        const float g4 = __shfl_up(f4, 2, 64);
        const float g5 = __shfl_up(f5, 2, 64);
        const float g6 = __shfl_up(f6, 2, 64);
        const float g7 = __shfl_up(f7, 2, 64);
        const float q1 = __shfl_down(p1, 2, 64);
        const float q2 = __shfl_down(p2, 2, 64);
        const float q3 = __shfl_down(p3, 2, 64);
        const float q4 = __shfl_down(p4, 2, 64);
        const float q5 = __shfl_down(p5, 2, 64);
        const float q6 = __shfl_down(p6, 2, 64);
        const float q7 = __shfl_down(p7, 2, 64);

        const float S3 = fmaf(mL1, sL1, fmaf(mR1, sR1, s));
        half8 hv;
        hv[0] = (_Float16)fmaf(mL2, g1, S3);
        hv[1] = (_Float16)fmaf(mL2, g2, fmaf(mR2, q1, S3));
        hv[2] = (_Float16)fmaf(mL2, g3, fmaf(mR2, q2, S3));
        hv[3] = (_Float16)fmaf(mL2, g4, fmaf(mR2, q3, S3));
        hv[4] = (_Float16)fmaf(mL2, g5, fmaf(mR2, q4, S3));
        hv[5] = (_Float16)fmaf(mL2, g6, fmaf(mR2, q5, S3));
        hv[6] = (_Float16)fmaf(mL2, g7, fmaf(mR2, q6, S3));
        hv[7] = (_Float16)fmaf(mR2, q7, S3);

        const int r = r0 + k;
        *(half8*)(hbuf + ((size_t)(r >> 9) * HP + (r & 511) + PADT) * W + col0) = hv;
    }
}

// ---------------------------------------------------------------------------
// k2: vertical 31-box over padded hrow (registers, slide +-1) + weight.
// NATURAL block order: block g outputs global rows [32g, 32g+32) -> reads
// hrow rows produced by k1 block g (+-1 halo) -> same-XCD L2 hits.
// Wave owns 8 rows x full width; lane owns 8 cols; ALL loads unconditional.
// ---------------------------------------------------------------------------
__global__ __launch_bounds__(256, 4) void main_kernel(const float* __restrict__ tgt,
                                                      const float* __restrict__ inp,
                                                      const _Float16* __restrict__ hbuf,
                                                      float4* __restrict__ partials) {
    const int tid  = threadIdx.x;
    const int lane = tid & 63;
    const int wv   = tid >> 6;
    const int g    = blockIdx.x;
    const int img  = g >> 4;                      // 16 blocks per image
    const int band = (g & 15) * 4 + wv;           // 0..63
    const int r0   = band * RB;
    const int col0 = lane * 8;

    const float*    timg = tgt  + (size_t)img * H * W;
    const float*    iimg = inp  + (size_t)img * H * W;
    const _Float16* hrp  = hbuf + (size_t)img * HP * W;   // padded base

    // ---- init box for h=r0: padded hrow rows r0+1 .. r0+31 ----------------
    float box[8];
    #pragma unroll
    for (int q = 0; q < 8; ++q) box[q] = 0.f;
    #pragma unroll
    for (int j = 0; j < 31; ++j) {
        const half8 hv = *(const half8*)(hrp + (size_t)(r0 + 1 + j) * W + col0);
        #pragma unroll
        for (int q = 0; q < 8; ++q) box[q] += (float)hv[q];
    }

    const float inv = 1.0f / 961.0f;
    float aI = 0.f, aA = 0.f, aB = 0.f;

    #pragma unroll
    for (int st = 0; st < RB; ++st) {
        const int h = r0 + st;
        // slide: += hrow[h+15] - hrow[h-16]  (padded rows h+31 / h; always
        // in-bounds <= 542 < 543, zero pads -> unconditional)
        if (st > 0) {                        // compile-time after full unroll
            const half8 a = *(const half8*)(hrp + (size_t)(h + 31) * W + col0);
            const half8 s = *(const half8*)(hrp + (size_t)h * W + col0);
            #pragma unroll
            for (int q = 0; q < 8; ++q) box[q] += (float)a[q] - (float)s[q];
        }
        // center rows: single-use -> nontemporal (keep L2/L3 for hrow)
        const floatx4 t0 = __builtin_nontemporal_load((const floatx4*)(timg + (size_t)h * W + col0));
        const floatx4 t1 = __builtin_nontemporal_load((const floatx4*)(timg + (size_t)h * W + col0 + 4));
        const floatx4 i0 = __builtin_nontemporal_load((const floatx4*)(iimg + (size_t)h * W + col0));
        const floatx4 i1 = __builtin_nontemporal_load((const floatx4*)(iimg + (size_t)h * W + col0 + 4));
        const float tv[8] = {t0[0], t0[1], t0[2], t0[3], t1[0], t1[1], t1[2], t1[3]};
        const float iv[8] = {i0[0], i0[1], i0[2], i0[3], i1[0], i1[1], i1[2], i1[3]};

        #pragma unroll
        for (int k = 0; k < 8; ++k) {
            const float wgt = fmaf(5.0f, fabsf(fmaf(box[k], inv, -tv[k])), 1.0f);
            const float tw  = tv[k] * wgt;
            aI = fmaf(iv[k], tw, aI);
            aA = fmaf(iv[k], wgt, aA);
            aB += tw;
        }
    }

    // ---- wave reduction (64 lanes) ----------------------------------------
    #pragma unroll
    for (int off = 32; off > 0; off >>= 1) {
        aI += __shfl_down(aI, off, 64);
        aA += __shfl_down(aA, off, 64);
        aB += __shfl_down(aB, off, 64);
    }
    __shared__ float sm[12];
    if (lane == 0) { sm[wv] = aI; sm[4 + wv] = aA; sm[8 + wv] = aB; }
    __syncthreads();
    if (tid == 0) {
        float4 o;
        o.x = sm[0] + sm[1] + sm[2] + sm[3];
        o.y = sm[4] + sm[5] + sm[6] + sm[7];
        o.z = sm[8] + sm[9] + sm[10] + sm[11];
        o.w = 0.f;
        partials[g] = o;
    }
}

// ---------------------------------------------------------------------------
// Reduce K2_BLOCKS (1024) partials + finalize. One block, 1024 threads.
// ---------------------------------------------------------------------------
__global__ __launch_bounds__(1024) void reduce_kernel(const float4* __restrict__ partials,
                                                      float* __restrict__ out) {
    const int tid = threadIdx.x;
    const float4 v = partials[tid];          // exactly 1024 entries
    float aI = v.x, aA = v.y, aB = v.z;
    #pragma unroll
    for (int off = 32; off > 0; off >>= 1) {
        aI += __shfl_down(aI, off, 64);
        aA += __shfl_down(aA, off, 64);
        aB += __shfl_down(aB, off, 64);
    }
    __shared__ float s[3][16];
    const int wvx = tid >> 6, ln = tid & 63;
    if (ln == 0) { s[0][wvx] = aI; s[1][wvx] = aA; s[2][wvx] = aB; }
    __syncthreads();
    if (tid == 0) {
        float I = 0.f, A = 0.f, Bv = 0.f;
        #pragma unroll
        for (int k = 0; k < 16; ++k) { I += s[0][k]; A += s[1][k]; Bv += s[2][k]; }
        out[0] = 1.0f - (2.0f * I + 1.0f) / (A + Bv + 1.0f);
    }
}

extern "C" void kernel_launch(void* const* d_in, const int* in_sizes, int n_in,
                              void* d_out, int out_size, void* d_ws, size_t ws_size,
                              hipStream_t stream) {
    const float* inp = (const float*)d_in[0];   // "input"
    const float* tgt = (const float*)d_in[1];   // "target"
    float* out = (float*)d_out;

    // workspace layout:
    //   [0, 35586048)            fp16 padded hrow (64 * 543 * 512 * 2 B)
    //   [35586048, +16 KB)       per-block partials (float4 x 1024)
    _Float16* hbuf = (_Float16*)d_ws;
    float4* partials = (float4*)((char*)d_ws + (size_t)BATCH * HP * W * sizeof(_Float16));

    hrow_kernel<<<K1_BLOCKS, 256, 0, stream>>>(tgt, hbuf);
    main_kernel<<<K2_BLOCKS, 256, 0, stream>>>(tgt, inp, hbuf, partials);
    reduce_kernel<<<1, 1024, 0, stream>>>(partials, out);
}

// Round 9
// 168.865 us; speedup vs baseline: 1.0467x; 1.0467x over previous
//
#include <hip/hip_runtime.h>

// WeightedDiceLoss on MI355X -- round 16: TLP doubling + cache-sane loads.
// R15 post-mortem: main_kernel 42.3us, 3.1 TB/s, VGPR 32, occupancy 29%.
// The compiler refuses to software-pipeline (3 failed ILP rounds: R9/R14/R15)
// -> the remaining latency-hiding lever is THREAD parallelism. Also the
// nontemporal hint backfired: FETCH 111.6 -> 129.5 MB (NT bypasses L3, but
// k2's tgt re-read IS L3-resident after k1: 67+33.5 MB << 256 MB).
// Changes:
//   * RB=4, 2048 blocks for BOTH k1 and k2 -> 8 blocks/CU, 32 waves/CU
//     (VGPR 32 permits 8 waves/SIMD). ~2x bytes in flight at identical
//     per-wave behavior. Init redundancy rises to ~303 MB of L2 traffic
//     (~9 us of L2 time at 34.5 TB/s -- affordable; HBM unchanged).
//   * k1 block i and k2 block i own the SAME 16 image rows (natural order
//     kept) -> producer/consumer share an XCD L2.
//   * NT removed everywhere; plain loads let tgt hit L3 in k2.
//   * k1: all 8 row-loads staged before any window compute.
//
// input, target: (64,1,512,512) fp32. Output: scalar fp32.
// weight = 1 + 5*|box31(target) - target|; loss = 1 - (2*I+1)/(A+B+1).

#define BATCH 64
#define H     512
#define W     512
#define PADT  16                       // top zero rows (image rows -16..-1)
#define PADB  15                       // bottom zero rows (rows 512..526)
#define HP    (H + PADT + PADB)        // 543 padded hrow rows per image
#define K1_BLOCKS 2048                 // 8192 waves x 4 rows = 32768 rows
#define RB    4                        // rows per k2 wave-task
#define K2_BLOCKS 2048                 // 8192 wave-tasks: 64 img x 128 bands

typedef _Float16 half8  __attribute__((ext_vector_type(8)));
typedef float    floatx4 __attribute__((ext_vector_type(4)));

// ---------------------------------------------------------------------------
// k1: hrow[r][x] = sum_{dx=-15..15} tgt[r][x+dx] (zero col padding), fp16,
// stored at padded row (r&511)+PADT of image r>>9. Also zeroes the pad rows.
// Block i covers global rows [16i, 16i+16) -- aligned with k2 block i.
// ---------------------------------------------------------------------------
__global__ __launch_bounds__(256) void hrow_kernel(const float* __restrict__ tgt,
                                                   _Float16* __restrict__ hbuf) {
    const int tid  = threadIdx.x;
    const int lane = tid & 63;
    const int wid  = blockIdx.x * 4 + (tid >> 6);   // 0..8191
    const int col0 = lane * 8;
    const int r0   = wid * 4;                       // first of 4 rows

    const float mL1 = (lane >= 1) ? 1.f : 0.f;
    const float mR1 = (lane <= 62) ? 1.f : 0.f;
    const float mL2 = (lane >= 2) ? 1.f : 0.f;
    const float mR2 = (lane <= 61) ? 1.f : 0.f;

    // ---- zero the pad rows (16 top + 15 bottom per image) -----------------
    if (wid < BATCH * 32) {
        const int img = wid >> 5, p = wid & 31;     // p = 0..31
        if (p < 31) {
            const int row = (p < PADT) ? p : p + H; // [0,16) u [528,543)
            half8 z = {};
            *(half8*)(hbuf + ((size_t)img * HP + row) * W + col0) = z;
        }
    }

    // ---- stage ALL 8 loads before any compute (max loads in flight) -------
    floatx4 va[4][2];
    #pragma unroll
    for (int k = 0; k < 4; ++k) {
        const float* trow = tgt + (size_t)(r0 + k) * W + col0;
        va[k][0] = *(const floatx4*)(trow);
        va[k][1] = *(const floatx4*)(trow + 4);
    }

    // ---- 4 horizontal 31-windows (verified segment-sum) -------------------
    #pragma unroll
    for (int k = 0; k < 4; ++k) {
        const float p1 = va[k][0][0];
        const float p2 = p1 + va[k][0][1];
        const float p3 = p2 + va[k][0][2];
        const float p4 = p3 + va[k][0][3];
        const float p5 = p4 + va[k][1][0];
        const float p6 = p5 + va[k][1][1];
        const float p7 = p6 + va[k][1][2];
        const float s  = p7 + va[k][1][3];
        const float f1 = s - p1, f2 = s - p2, f3 = s - p3, f4 = s - p4;
        const float f5 = s - p5, f6 = s - p6, f7 = s - p7;

        const float sL1 = __shfl_up(s, 1, 64);
        const float sR1 = __shfl_down(s, 1, 64);
        const float g1 = __shfl_up(f1, 2, 64);
        const float g2 = __shfl_up(f2, 2, 64);
        const float g3 = __shfl_up(f3, 2, 64);
        const float g4 = __shfl_up(f4, 2, 64);
        const float g5 = __shfl_up(f5, 2, 64);
        const float g6 = __shfl_up(f6, 2, 64);
        const float g7 = __shfl_up(f7, 2, 64);
        const float q1 = __shfl_down(p1, 2, 64);
        const float q2 = __shfl_down(p2, 2, 64);
        const float q3 = __shfl_down(p3, 2, 64);
        const float q4 = __shfl_down(p4, 2, 64);
        const float q5 = __shfl_down(p5, 2, 64);
        const float q6 = __shfl_down(p6, 2, 64);
        const float q7 = __shfl_down(p7, 2, 64);

        const float S3 = fmaf(mL1, sL1, fmaf(mR1, sR1, s));
        half8 hv;
        hv[0] = (_Float16)fmaf(mL2, g1, S3);
        hv[1] = (_Float16)fmaf(mL2, g2, fmaf(mR2, q1, S3));
        hv[2] = (_Float16)fmaf(mL2, g3, fmaf(mR2, q2, S3));
        hv[3] = (_Float16)fmaf(mL2, g4, fmaf(mR2, q3, S3));
        hv[4] = (_Float16)fmaf(mL2, g5, fmaf(mR2, q4, S3));
        hv[5] = (_Float16)fmaf(mL2, g6, fmaf(mR2, q5, S3));
        hv[6] = (_Float16)fmaf(mL2, g7, fmaf(mR2, q6, S3));
        hv[7] = (_Float16)fmaf(mR2, q7, S3);

        const int r = r0 + k;
        *(half8*)(hbuf + ((size_t)(r >> 9) * HP + (r & 511) + PADT) * W + col0) = hv;
    }
}

// ---------------------------------------------------------------------------
// k2: vertical 31-box over padded hrow (registers, slide +-1) + weight.
// NATURAL block order: block i outputs global rows [16i, 16i+16) -> reads
// hrow rows produced by k1 block i (+-1 halo) -> same-XCD L2 hits.
// Wave owns 4 rows x full width; lane owns 8 cols; ALL loads unconditional.
// 2048 blocks -> 8 blocks/CU -> 32 waves/CU at VGPR~32.
// ---------------------------------------------------------------------------
__global__ __launch_bounds__(256) void main_kernel(const float* __restrict__ tgt,
                                                   const float* __restrict__ inp,
                                                   const _Float16* __restrict__ hbuf,
                                                   float4* __restrict__ partials) {
    const int tid  = threadIdx.x;
    const int lane = tid & 63;
    const int wv   = tid >> 6;
    const int g    = blockIdx.x;
    const int img  = g >> 5;                      // 32 blocks per image
    const int band = (g & 31) * 4 + wv;           // 0..127
    const int r0   = band * RB;
    const int col0 = lane * 8;

    const float*    timg = tgt  + (size_t)img * H * W;
    const float*    iimg = inp  + (size_t)img * H * W;
    const _Float16* hrp  = hbuf + (size_t)img * HP * W;   // padded base

    // ---- init box for h=r0: padded hrow rows r0+1 .. r0+31 ----------------
    float box[8];
    #pragma unroll
    for (int q = 0; q < 8; ++q) box[q] = 0.f;
    #pragma unroll
    for (int j = 0; j < 31; ++j) {
        const half8 hv = *(const half8*)(hrp + (size_t)(r0 + 1 + j) * W + col0);
        #pragma unroll
        for (int q = 0; q < 8; ++q) box[q] += (float)hv[q];
    }

    const float inv = 1.0f / 961.0f;
    float aI = 0.f, aA = 0.f, aB = 0.f;

    #pragma unroll
    for (int st = 0; st < RB; ++st) {
        const int h = r0 + st;
        // slide: += hrow[h+15] - hrow[h-16]  (padded rows h+31 / h; always
        // in-bounds <= 542 < 543, zero pads -> unconditional)
        if (st > 0) {                        // compile-time after full unroll
            const half8 a = *(const half8*)(hrp + (size_t)(h + 31) * W + col0);
            const half8 s = *(const half8*)(hrp + (size_t)h * W + col0);
            #pragma unroll
            for (int q = 0; q < 8; ++q) box[q] += (float)a[q] - (float)s[q];
        }
        // center rows: tgt is L3-resident after k1 (plain loads, no NT)
        const floatx4 t0 = *(const floatx4*)(timg + (size_t)h * W + col0);
        const floatx4 t1 = *(const floatx4*)(timg + (size_t)h * W + col0 + 4);
        const floatx4 i0 = *(const floatx4*)(iimg + (size_t)h * W + col0);
        const floatx4 i1 = *(const floatx4*)(iimg + (size_t)h * W + col0 + 4);
        const float tv[8] = {t0[0], t0[1], t0[2], t0[3], t1[0], t1[1], t1[2], t1[3]};
        const float iv[8] = {i0[0], i0[1], i0[2], i0[3], i1[0], i1[1], i1[2], i1[3]};

        #pragma unroll
        for (int k = 0; k < 8; ++k) {
            const float wgt = fmaf(5.0f, fabsf(fmaf(box[k], inv, -tv[k])), 1.0f);
            const float tw  = tv[k] * wgt;
            aI = fmaf(iv[k], tw, aI);
            aA = fmaf(iv[k], wgt, aA);
            aB += tw;
        }
    }

    // ---- wave reduction (64 lanes) ----------------------------------------
    #pragma unroll
    for (int off = 32; off > 0; off >>= 1) {
        aI += __shfl_down(aI, off, 64);
        aA += __shfl_down(aA, off, 64);
        aB += __shfl_down(aB, off, 64);
    }
    __shared__ float sm[12];
    if (lane == 0) { sm[wv] = aI; sm[4 + wv] = aA; sm[8 + wv] = aB; }
    __syncthreads();
    if (tid == 0) {
        float4 o;
        o.x = sm[0] + sm[1] + sm[2] + sm[3];
        o.y = sm[4] + sm[5] + sm[6] + sm[7];
        o.z = sm[8] + sm[9] + sm[10] + sm[11];
        o.w = 0.f;
        partials[g] = o;
    }
}

// ---------------------------------------------------------------------------
// Reduce K2_BLOCKS (2048) partials + finalize. One block, 1024 threads.
// ---------------------------------------------------------------------------
__global__ __launch_bounds__(1024) void reduce_kernel(const float4* __restrict__ partials,
                                                      float* __restrict__ out) {
    const int tid = threadIdx.x;
    const float4 v0 = partials[tid];
    const float4 v1 = partials[tid + 1024];
    float aI = v0.x + v1.x, aA = v0.y + v1.y, aB = v0.z + v1.z;
    #pragma unroll
    for (int off = 32; off > 0; off >>= 1) {
        aI += __shfl_down(aI, off, 64);
        aA += __shfl_down(aA, off, 64);
        aB += __shfl_down(aB, off, 64);
    }
    __shared__ float s[3][16];
    const int wvx = tid >> 6, ln = tid & 63;
    if (ln == 0) { s[0][wvx] = aI; s[1][wvx] = aA; s[2][wvx] = aB; }
    __syncthreads();
    if (tid == 0) {
        float I = 0.f, A = 0.f, Bv = 0.f;
        #pragma unroll
        for (int k = 0; k < 16; ++k) { I += s[0][k]; A += s[1][k]; Bv += s[2][k]; }
        out[0] = 1.0f - (2.0f * I + 1.0f) / (A + Bv + 1.0f);
    }
}

extern "C" void kernel_launch(void* const* d_in, const int* in_sizes, int n_in,
                              void* d_out, int out_size, void* d_ws, size_t ws_size,
                              hipStream_t stream) {
    const float* inp = (const float*)d_in[0];   // "input"
    const float* tgt = (const float*)d_in[1];   // "target"
    float* out = (float*)d_out;

    // workspace layout:
    //   [0, 35586048)            fp16 padded hrow (64 * 543 * 512 * 2 B)
    //   [35586048, +32 KB)       per-block partials (float4 x 2048)
    _Float16* hbuf = (_Float16*)d_ws;
    float4* partials = (float4*)((char*)d_ws + (size_t)BATCH * HP * W * sizeof(_Float16));

    hrow_kernel<<<K1_BLOCKS, 256, 0, stream>>>(tgt, hbuf);
    main_kernel<<<K2_BLOCKS, 256, 0, stream>>>(tgt, inp, hbuf, partials);
    reduce_kernel<<<1, 1024, 0, stream>>>(partials, out);
}

// Round 10
// 164.096 us; speedup vs baseline: 1.0771x; 1.0291x over previous
//
#include <hip/hip_runtime.h>

// WeightedDiceLoss on MI355X -- round 17: route tgt through the WRITTEN path.
// R15/R16 fetch arithmetic established the cache law for this harness:
//   * hrow window reads (188-310 MB of L2 traffic) are ~fully cache-absorbed
//     -> k1-WRITTEN data stays hot for k2 (dirty lines persist).
//   * the k2 tgt re-read is a guaranteed 67 MB HBM tax (with NT *and*
//     without) -> k1-READ data does not survive (clean streamed lines evict).
// R16 also falsified the pure-TLP theory: occupancy 29->49% made things
// WORSE (42->50 us) because RB=4 doubled hrow read redundancy.
// Fixes:
//   * k1 additionally writes tgt16 (fp16 copy, 33.5 MB) -> k2's center-tgt
//     read comes from the written/cache-hot path. k2 HBM fetch ~141 -> ~70-100.
//   * k2: RB=8 (low redundancy) but HALF-WIDTH waves (lane owns 4 cols of a
//     256-col half) -> 8192 wave-tasks, 2048 blocks, 8 blocks/CU.
//   * k1 block i and k2 block i own the same 16 image rows (XCD pairing).
// Precision: tgt16 RTN err <= 4.9e-4/px, unbiased over 16.7M px -> loss err
// ~1e-5 (fp16 hrow at similar scale already passes with absmax 0.0).
//
// input, target: (64,1,512,512) fp32. Output: scalar fp32.
// weight = 1 + 5*|box31(target) - target|; loss = 1 - (2*I+1)/(A+B+1).

#define BATCH 64
#define H     512
#define W     512
#define PADT  16                       // top zero rows (image rows -16..-1)
#define PADB  15                       // bottom zero rows (rows 512..526)
#define HP    (H + PADT + PADB)        // 543 padded hrow rows per image
#define K1_BLOCKS 2048                 // 8192 waves x 4 rows = 32768 rows
#define RB    8                        // rows per k2 wave-task
#define K2_BLOCKS 2048                 // 8192 wave-tasks: 64img x 64band x 2half

typedef _Float16 half8  __attribute__((ext_vector_type(8)));
typedef _Float16 half4  __attribute__((ext_vector_type(4)));
typedef float    floatx4 __attribute__((ext_vector_type(4)));

// ---------------------------------------------------------------------------
// k1: hrow16[r] = horizontal 31-box of tgt row r (fp16, padded layout) AND
// tgt16[r] = fp16 copy of tgt row r. Block i covers rows [16i, 16i+16).
// ---------------------------------------------------------------------------
__global__ __launch_bounds__(256) void hrow_kernel(const float* __restrict__ tgt,
                                                   _Float16* __restrict__ hbuf,
                                                   _Float16* __restrict__ tbuf) {
    const int tid  = threadIdx.x;
    const int lane = tid & 63;
    const int wid  = blockIdx.x * 4 + (tid >> 6);   // 0..8191
    const int col0 = lane * 8;
    const int r0   = wid * 4;                       // first of 4 rows

    const float mL1 = (lane >= 1) ? 1.f : 0.f;
    const float mR1 = (lane <= 62) ? 1.f : 0.f;
    const float mL2 = (lane >= 2) ? 1.f : 0.f;
    const float mR2 = (lane <= 61) ? 1.f : 0.f;

    // ---- zero the hrow pad rows (16 top + 15 bottom per image) ------------
    if (wid < BATCH * 32) {
        const int img = wid >> 5, p = wid & 31;     // p = 0..31
        if (p < 31) {
            const int row = (p < PADT) ? p : p + H; // [0,16) u [528,543)
            half8 z = {};
            *(half8*)(hbuf + ((size_t)img * HP + row) * W + col0) = z;
        }
    }

    // ---- stage ALL 8 loads before any compute (max loads in flight) -------
    floatx4 va[4][2];
    #pragma unroll
    for (int k = 0; k < 4; ++k) {
        const float* trow = tgt + (size_t)(r0 + k) * W + col0;
        va[k][0] = *(const floatx4*)(trow);
        va[k][1] = *(const floatx4*)(trow + 4);
    }

    // ---- 4 horizontal 31-windows + fp16 tgt copies ------------------------
    #pragma unroll
    for (int k = 0; k < 4; ++k) {
        const float p1 = va[k][0][0];
        const float p2 = p1 + va[k][0][1];
        const float p3 = p2 + va[k][0][2];
        const float p4 = p3 + va[k][0][3];
        const float p5 = p4 + va[k][1][0];
        const float p6 = p5 + va[k][1][1];
        const float p7 = p6 + va[k][1][2];
        const float s  = p7 + va[k][1][3];
        const float f1 = s - p1, f2 = s - p2, f3 = s - p3, f4 = s - p4;
        const float f5 = s - p5, f6 = s - p6, f7 = s - p7;

        const float sL1 = __shfl_up(s, 1, 64);
        const float sR1 = __shfl_down(s, 1, 64);
        const float g1 = __shfl_up(f1, 2, 64);
        const float g2 = __shfl_up(f2, 2, 64);
        const float g3 = __shfl_up(f3, 2, 64);
        const float g4 = __shfl_up(f4, 2, 64);
        const float g5 = __shfl_up(f5, 2, 64);
        const float g6 = __shfl_up(f6, 2, 64);
        const float g7 = __shfl_up(f7, 2, 64);
        const float q1 = __shfl_down(p1, 2, 64);
        const float q2 = __shfl_down(p2, 2, 64);
        const float q3 = __shfl_down(p3, 2, 64);
        const float q4 = __shfl_down(p4, 2, 64);
        const float q5 = __shfl_down(p5, 2, 64);
        const float q6 = __shfl_down(p6, 2, 64);
        const float q7 = __shfl_down(p7, 2, 64);

        const float S3 = fmaf(mL1, sL1, fmaf(mR1, sR1, s));
        half8 hv;
        hv[0] = (_Float16)fmaf(mL2, g1, S3);
        hv[1] = (_Float16)fmaf(mL2, g2, fmaf(mR2, q1, S3));
        hv[2] = (_Float16)fmaf(mL2, g3, fmaf(mR2, q2, S3));
        hv[3] = (_Float16)fmaf(mL2, g4, fmaf(mR2, q3, S3));
        hv[4] = (_Float16)fmaf(mL2, g5, fmaf(mR2, q4, S3));
        hv[5] = (_Float16)fmaf(mL2, g6, fmaf(mR2, q5, S3));
        hv[6] = (_Float16)fmaf(mL2, g7, fmaf(mR2, q6, S3));
        hv[7] = (_Float16)fmaf(mR2, q7, S3);

        const int r = r0 + k;
        *(half8*)(hbuf + ((size_t)(r >> 9) * HP + (r & 511) + PADT) * W + col0) = hv;

        half8 tv16;
        #pragma unroll
        for (int q = 0; q < 4; ++q) tv16[q] = (_Float16)va[k][0][q];
        #pragma unroll
        for (int q = 0; q < 4; ++q) tv16[4 + q] = (_Float16)va[k][1][q];
        *(half8*)(tbuf + (size_t)r * W + col0) = tv16;
    }
}

// ---------------------------------------------------------------------------
// k2: vertical 31-box over padded hrow (registers, slide +-1) + weight.
// Half-width waves: wave-task = (img, band of 8 rows, 256-col half); lane
// owns 4 cols. ALL loads unconditional; tgt center from WRITTEN tgt16.
// Block i reads rows produced by k1 block i (+-halo) -> same-XCD L2.
// ---------------------------------------------------------------------------
__global__ __launch_bounds__(256) void main_kernel(const float* __restrict__ inp,
                                                   const _Float16* __restrict__ hbuf,
                                                   const _Float16* __restrict__ tbuf,
                                                   float4* __restrict__ partials) {
    const int tid  = threadIdx.x;
    const int lane = tid & 63;
    const int wv   = tid >> 6;
    const int wtid = blockIdx.x * 4 + wv;         // 0..8191
    const int img  = wtid >> 7;                   // 128 wave-tasks per image
    const int r    = wtid & 127;
    const int band = r >> 1;                      // 0..63
    const int half = r & 1;                       // 256-col half
    const int r0   = band * RB;
    const int col0 = half * 256 + lane * 4;

    const float*    iimg = inp  + (size_t)img * H * W;
    const _Float16* hrp  = hbuf + (size_t)img * HP * W;   // padded base
    const _Float16* trp  = tbuf + (size_t)img * H * W;

    // ---- init box for h=r0: padded hrow rows r0+1 .. r0+31 ----------------
    float box[4];
    #pragma unroll
    for (int q = 0; q < 4; ++q) box[q] = 0.f;
    #pragma unroll
    for (int j = 0; j < 31; ++j) {
        const half4 hv = *(const half4*)(hrp + (size_t)(r0 + 1 + j) * W + col0);
        #pragma unroll
        for (int q = 0; q < 4; ++q) box[q] += (float)hv[q];
    }

    const float inv = 1.0f / 961.0f;
    float aI = 0.f, aA = 0.f, aB = 0.f;

    #pragma unroll
    for (int st = 0; st < RB; ++st) {
        const int h = r0 + st;
        // slide: += hrow[h+15] - hrow[h-16]  (padded rows h+31 / h; always
        // in-bounds <= 542 < 543, zero pads -> unconditional)
        if (st > 0) {                        // compile-time after full unroll
            const half4 a = *(const half4*)(hrp + (size_t)(h + 31) * W + col0);
            const half4 s = *(const half4*)(hrp + (size_t)h * W + col0);
            #pragma unroll
            for (int q = 0; q < 4; ++q) box[q] += (float)a[q] - (float)s[q];
        }
        // center: inp fp32 (compulsory HBM), tgt fp16 from WRITTEN buffer
        const floatx4 iv4 = *(const floatx4*)(iimg + (size_t)h * W + col0);
        const half4   tv4 = *(const half4*)(trp + (size_t)h * W + col0);

        #pragma unroll
        for (int k = 0; k < 4; ++k) {
            const float tv  = (float)tv4[k];
            const float wgt = fmaf(5.0f, fabsf(fmaf(box[k], inv, -tv)), 1.0f);
            const float tw  = tv * wgt;
            aI = fmaf(iv4[k], tw, aI);
            aA = fmaf(iv4[k], wgt, aA);
            aB += tw;
        }
    }

    // ---- wave reduction (64 lanes) ----------------------------------------
    #pragma unroll
    for (int off = 32; off > 0; off >>= 1) {
        aI += __shfl_down(aI, off, 64);
        aA += __shfl_down(aA, off, 64);
        aB += __shfl_down(aB, off, 64);
    }
    __shared__ float sm[12];
    if (lane == 0) { sm[wv] = aI; sm[4 + wv] = aA; sm[8 + wv] = aB; }
    __syncthreads();
    if (tid == 0) {
        float4 o;
        o.x = sm[0] + sm[1] + sm[2] + sm[3];
        o.y = sm[4] + sm[5] + sm[6] + sm[7];
        o.z = sm[8] + sm[9] + sm[10] + sm[11];
        o.w = 0.f;
        partials[blockIdx.x] = o;
    }
}

// ---------------------------------------------------------------------------
// Reduce K2_BLOCKS (2048) partials + finalize. One block, 1024 threads.
// ---------------------------------------------------------------------------
__global__ __launch_bounds__(1024) void reduce_kernel(const float4* __restrict__ partials,
                                                      float* __restrict__ out) {
    const int tid = threadIdx.x;
    const float4 v0 = partials[tid];
    const float4 v1 = partials[tid + 1024];
    float aI = v0.x + v1.x, aA = v0.y + v1.y, aB = v0.z + v1.z;
    #pragma unroll
    for (int off = 32; off > 0; off >>= 1) {
        aI += __shfl_down(aI, off, 64);
        aA += __shfl_down(aA, off, 64);
        aB += __shfl_down(aB, off, 64);
    }
    __shared__ float s[3][16];
    const int wvx = tid >> 6, ln = tid & 63;
    if (ln == 0) { s[0][wvx] = aI; s[1][wvx] = aA; s[2][wvx] = aB; }
    __syncthreads();
    if (tid == 0) {
        float I = 0.f, A = 0.f, Bv = 0.f;
        #pragma unroll
        for (int k = 0; k < 16; ++k) { I += s[0][k]; A += s[1][k]; Bv += s[2][k]; }
        out[0] = 1.0f - (2.0f * I + 1.0f) / (A + Bv + 1.0f);
    }
}

extern "C" void kernel_launch(void* const* d_in, const int* in_sizes, int n_in,
                              void* d_out, int out_size, void* d_ws, size_t ws_size,
                              hipStream_t stream) {
    const float* inp = (const float*)d_in[0];   // "input"
    const float* tgt = (const float*)d_in[1];   // "target"
    float* out = (float*)d_out;

    // workspace layout:
    //   [0, 35586048)            fp16 padded hrow (64 * 543 * 512 * 2 B)
    //   [35586048, 69140480)     fp16 tgt copy   (64 * 512 * 512 * 2 B)
    //   [69140480, +32 KB)       per-block partials (float4 x 2048)
    _Float16* hbuf = (_Float16*)d_ws;
    _Float16* tbuf = (_Float16*)((char*)d_ws + (size_t)BATCH * HP * W * sizeof(_Float16));
    float4* partials = (float4*)((char*)d_ws + (size_t)BATCH * (HP + H) * W * sizeof(_Float16));

    hrow_kernel<<<K1_BLOCKS, 256, 0, stream>>>(tgt, hbuf, tbuf);
    main_kernel<<<K2_BLOCKS, 256, 0, stream>>>(inp, hbuf, tbuf, partials);
    reduce_kernel<<<1, 1024, 0, stream>>>(partials, out);
}